// Round 6
// baseline (443.247 us; speedup 1.0000x reference)
//
#include <hip/hip_runtime.h>
#include <cstdint>
#include <cstddef>

// Problem constants
#define L_   256
#define Q_   21
#define M_   8192
#define QQ   441
#define JCH  32            // j-blocks staged per barrier in k_main
#define SCALE    32.0f     // J scaled by 32 before fp8 quantization
#define INVSCALE 0.03125f
#define NPAIR ((L_ * (L_ - 1)) / 2)   // 32640 valid (i,j) pairs
#define PPB   16           // pairs per prep block
#define PREPB (NPAIR / PPB)           // 2040 blocks, exact

// Jt block layout (per (i,j)): 21 rows (k = symbol), each row 24 B =
// 21 fp8(e4m3, J*32) elems a=0..20 + 3 zero pad. Row stride 6 dwords.
// Block padded to 512 B (128 dwords). Jt total = 65536 * 512 B = 32 MiB.
//
// ws layout (floats at base):
//   acc[0]=wsum  acc[2]=h2_sum
//   acc[4..259]   = 256 J2 partial slots
//   acc[260..387] = 128 ll partial slots
//   [2048 .. +2MiB)  seqsP: dword[jq*M + b] = symbols j=4jq..4jq+3 (bytes)
//   [2048+2MiB ..)   Jt (fp8 blocks)

typedef float v2f __attribute__((ext_vector_type(2)));

__device__ __forceinline__ float block_reduce_sum(float v) {
    __shared__ float s[256];
    int t = threadIdx.x;
    __syncthreads();           // guard against reuse hazard
    s[t] = v;
    __syncthreads();
#pragma unroll
    for (int o = 128; o > 0; o >>= 1) {
        if (t < o) s[t] += s[t + o];
        __syncthreads();
    }
    return s[0];
}

__device__ __forceinline__ int tri_invert(int n) {
    // largest i with i(i-1)/2 <= n
    int i = (int)((1.0f + sqrtf(8.0f * (float)n + 1.0f)) * 0.5f);
    while (i * (i - 1) / 2 > n) --i;
    while (i * (i - 1) / 2 + i <= n) ++i;
    return i;
}

// ---- prep A: J fp32 -> Jt fp8 transpose + reg_J; bulk streaming ----
// 2040 blocks x 16 pairs: single load phase (coalesced, J^2 inline),
// one barrier, single pack phase (coalesced stores).
__global__ __launch_bounds__(256) void k_prep(const float* __restrict__ J,
                                              unsigned* __restrict__ Jt,
                                              float* __restrict__ acc) {
    __shared__ float sB[PPB * QQ];   // 28224 B
    const int t = threadIdx.x;
    const int n0 = blockIdx.x * PPB;

    float v2acc = 0.f;
#pragma unroll 1
    for (int p = 0; p < PPB; ++p) {
        const int n = n0 + p;
        const int i = tri_invert(n);
        const int j = n - i * (i - 1) / 2;
        const float* blk = J + ((size_t)i * L_ + j) * QQ;
        float* dst = sB + p * QQ;
        for (int x = t; x < QQ; x += 256) {
            float v = blk[x];
            dst[x] = v;
            v2acc += v * v;
        }
    }
    __syncthreads();

    // pack: thread t handles pair p = t>>4, dwords d = (t&15) + 16u
    {
        const int p = t >> 4;
        const int n = n0 + p;
        const int i = tri_invert(n);
        const int j = n - i * (i - 1) / 2;
        const size_t ij = (size_t)i * L_ + j;
        const float* s = sB + p * QQ;
#pragma unroll
        for (int u = 0; u < 8; ++u) {
            const int d = (t & 15) + (u << 4);       // 0..127
            const int kr = d / 6;
            const int dw = d - 6 * kr;
            const int a0 = dw * 4;
            unsigned outw = 0;
            if (kr < Q_) {
                float x0 = (a0 + 0 < Q_) ? s[(a0 + 0) * Q_ + kr] : 0.f;
                float x1 = (a0 + 1 < Q_) ? s[(a0 + 1) * Q_ + kr] : 0.f;
                float x2 = (a0 + 2 < Q_) ? s[(a0 + 2) * Q_ + kr] : 0.f;
                float x3 = (a0 + 3 < Q_) ? s[(a0 + 3) * Q_ + kr] : 0.f;
                outw = (unsigned)__builtin_amdgcn_cvt_pk_fp8_f32(x0 * SCALE, x1 * SCALE, 0, false);
                outw = (unsigned)__builtin_amdgcn_cvt_pk_fp8_f32(x2 * SCALE, x3 * SCALE, (int)outw, true);
            }
            Jt[ij * 128 + d] = outw;
        }
    }

    float r = block_reduce_sum(v2acc);
    if (t == 0) atomicAdd(&acc[4 + (blockIdx.x & 255)], r);
}

// ---- prep B: pack seqs + wsum + h2 (33 small blocks) ----
__global__ __launch_bounds__(256) void k_prep2(const int* __restrict__ seqs,
                                               const float* __restrict__ w,
                                               const float* __restrict__ h,
                                               unsigned* __restrict__ seqsP,
                                               float* __restrict__ acc) {
    const int bid = blockIdx.x;
    const int t = threadIdx.x;
    if (bid < 32) {
        const int b = bid * 256 + t;
        const int4* row = reinterpret_cast<const int4*>(seqs + (size_t)b * L_);
#pragma unroll 4
        for (int jq = 0; jq < L_ / 4; ++jq) {
            int4 v = row[jq];
            unsigned p = (unsigned)(v.x & 255) | ((unsigned)(v.y & 255) << 8) |
                         ((unsigned)(v.z & 255) << 16) | ((unsigned)(v.w & 255) << 24);
            seqsP[jq * M_ + b] = p;
        }
    } else {
        float v = 0.f;
        for (int x = t; x < M_; x += 256) v += w[x];
        float r = block_reduce_sum(v);
        if (t == 0) acc[0] = r;
        float v2 = 0.f;
        for (int x = t; x < L_ * Q_; x += 256) { float y = h[x]; v2 += y * y; }
        float r2 = block_reduce_sum(v2);
        if (t == 0) acc[2] = r2;
    }
}

// ---- main: LDS-staged fp8 gather + log_softmax + weighted ll ----
__global__ __launch_bounds__(256, 8) void k_main(const unsigned* __restrict__ Jt,
                                                 const float* __restrict__ h,
                                                 const unsigned* __restrict__ seqsP,
                                                 const float* __restrict__ weights,
                                                 float* __restrict__ acc) {
    __shared__ unsigned sJ[JCH * 128];   // 16 KiB: JCH blocks x 128 dwords

    const int bid = blockIdx.x;
    const int i = (L_ - 1) - (bid >> 5);              // heavy blocks first
    const int b = ((bid & 31) << 8) + threadIdx.x;    // [0, 8192)

    // packed accumulators: acc2[m] covers logits a=2m, 2m+1 (scaled by SCALE)
    v2f acc2[11];
    const float* hp = h + i * Q_;
#pragma unroll
    for (int m = 0; m < 10; ++m) { acc2[m].x = hp[2*m] * SCALE; acc2[m].y = hp[2*m+1] * SCALE; }
    acc2[10].x = hp[20] * SCALE; acc2[10].y = 0.f;

    const unsigned* Jrow = Jt + (size_t)i * (256 * 128);  // dwords of row i

    for (int j0 = 0; j0 < i; j0 += JCH) {
        // stage JCH fp8 blocks: JCH*128 dwords = 1024 uint4, 4 per thread
        {
            const uint4* src = reinterpret_cast<const uint4*>(Jrow + j0 * 128);
            uint4* dst = reinterpret_cast<uint4*>(sJ);
#pragma unroll
            for (int n = 0; n < (JCH * 32) / 256; ++n) {
                dst[n * 256 + threadIdx.x] = src[n * 256 + threadIdx.x];
            }
        }
        __syncthreads();

        // packed indices for this stage: 8 dwords = 32 symbols
        unsigned idxw[JCH / 4];
#pragma unroll
        for (int q = 0; q < JCH / 4; ++q) {
            idxw[q] = seqsP[((j0 >> 2) + q) * M_ + b];
        }

        const int nj = min(i - j0, JCH);
#pragma unroll
        for (int jj = 0; jj < JCH; ++jj) {
            if (jj >= nj) break;
            const unsigned k = (idxw[jj >> 2] >> ((jj & 3) * 8)) & 255u;
            // row: block jj, row k -> uint2 index (jj*128 + k*6)/2
            const uint2* r = reinterpret_cast<const uint2*>(sJ) + (jj * 64 + k * 3);
            uint2 d0 = r[0], d1 = r[1], d2 = r[2];
            acc2[0]  += __builtin_amdgcn_cvt_pk_f32_fp8(d0.x, false);
            acc2[1]  += __builtin_amdgcn_cvt_pk_f32_fp8(d0.x, true);
            acc2[2]  += __builtin_amdgcn_cvt_pk_f32_fp8(d0.y, false);
            acc2[3]  += __builtin_amdgcn_cvt_pk_f32_fp8(d0.y, true);
            acc2[4]  += __builtin_amdgcn_cvt_pk_f32_fp8(d1.x, false);
            acc2[5]  += __builtin_amdgcn_cvt_pk_f32_fp8(d1.x, true);
            acc2[6]  += __builtin_amdgcn_cvt_pk_f32_fp8(d1.y, false);
            acc2[7]  += __builtin_amdgcn_cvt_pk_f32_fp8(d1.y, true);
            acc2[8]  += __builtin_amdgcn_cvt_pk_f32_fp8(d2.x, false);
            acc2[9]  += __builtin_amdgcn_cvt_pk_f32_fp8(d2.x, true);
            acc2[10] += __builtin_amdgcn_cvt_pk_f32_fp8(d2.y, false);
        }
        __syncthreads();
    }

    // unpack logits
    float l[21];
#pragma unroll
    for (int m = 0; m < 10; ++m) { l[2*m] = acc2[m].x * INVSCALE; l[2*m+1] = acc2[m].y * INVSCALE; }
    l[20] = acc2[10].x * INVSCALE;

    // label gather from packed seqs
    unsigned lw = seqsP[(i >> 2) * M_ + b];
    int lbl = (int)((lw >> ((i & 3) * 8)) & 255u);

    float m = l[0];
#pragma unroll
    for (int a = 1; a < 21; ++a) m = fmaxf(m, l[a]);
    float s = 0.f;
    float lv = l[0];
#pragma unroll
    for (int a = 0; a < 21; ++a) {
        s += __expf(l[a] - m);
        if (a > 0) lv = (a == lbl) ? l[a] : lv;
    }
    float ll = (lv - m) - __logf(s);
    float contrib = weights[b] * ll;

    float r = block_reduce_sum(contrib);
    if (threadIdx.x == 0) atomicAdd(&acc[260 + (bid & 127)], r);
}

// ---- finalize: reduce partial slots + compose outputs ----
__global__ void k_final(const float* __restrict__ acc, float* __restrict__ out) {
    int t = threadIdx.x;
    float j2p = acc[4 + t];                       // 256 J2 slots
    float j2 = block_reduce_sum(j2p);
    float llp = (t < 128) ? acc[260 + t] : 0.f;   // 128 ll slots
    float lls = block_reduce_sum(llp);
    if (t == 0) {
        float wsum = fmaxf(acc[0], 1e-12f);
        float nll = -lls / wsum;
        float reg = 0.5e-6f * acc[2] + 0.5e-4f * j2;
        out[0] = nll + reg;
        out[1] = nll;
        out[2] = reg;
    }
}

extern "C" void kernel_launch(void* const* d_in, const int* in_sizes, int n_in,
                              void* d_out, int out_size, void* d_ws, size_t ws_size,
                              hipStream_t stream) {
    const int*   seqs    = (const int*)d_in[0];
    const float* weights = (const float*)d_in[1];
    const float* h       = (const float*)d_in[2];
    const float* J       = (const float*)d_in[3];
    float* out = (float*)d_out;

    char* ws = (char*)d_ws;
    float*    acc   = (float*)ws;
    unsigned* seqsP = (unsigned*)(ws + 2048);
    unsigned* Jt    = (unsigned*)(ws + 2048 + (size_t)(L_ / 4) * M_ * sizeof(unsigned));

    hipMemsetAsync(d_ws, 0, 2048, stream);

    k_prep<<<PREPB, 256, 0, stream>>>(J, Jt, acc);
    k_prep2<<<33, 256, 0, stream>>>(seqs, weights, h, seqsP, acc);
    k_main<<<L_ * (M_ / 256), 256, 0, stream>>>(Jt, h, seqsP, weights, acc);
    k_final<<<1, 256, 0, stream>>>(acc, out);
}

// Round 7
// 429.043 us; speedup vs baseline: 1.0331x; 1.0331x over previous
//
#include <hip/hip_runtime.h>
#include <cstdint>
#include <cstddef>

// Problem constants
#define L_   256
#define Q_   21
#define M_   8192
#define QQ   441
#define JCH  32            // j-blocks staged per barrier in k_main
#define SCALE    32.0f     // J scaled by 32 before fp8 quantization
#define INVSCALE 0.03125f
#define NPAIR ((L_ * (L_ - 1)) / 2)   // 32640 valid (i,j) pairs
#define PPB   16           // pairs per prep block
#define PREPB (NPAIR / PPB)           // 2040 blocks, exact

// Jt block layout (per (i,j)): 21 rows (k = symbol), each row 24 B =
// 21 fp8(e4m3, J*32) elems a=0..20 + 3 zero pad. Row stride 6 dwords.
// Block padded to 512 B (128 dwords). Jt total = 65536 * 512 B = 32 MiB.
//
// ws layout (floats at base):
//   acc[0]=wsum  acc[2]=h2_sum
//   acc[4..259]   = 256 J2 partial slots
//   acc[260..387] = 128 ll partial slots
//   [2048 .. +2MiB)  seqsP: dword[jq*M + b] = symbols j=4jq..4jq+3 (bytes)
//   [2048+2MiB ..)   Jt (fp8 blocks)

typedef float v2f __attribute__((ext_vector_type(2)));

__device__ __forceinline__ float block_reduce_sum(float v) {
    __shared__ float s[256];
    int t = threadIdx.x;
    __syncthreads();           // guard against reuse hazard
    s[t] = v;
    __syncthreads();
#pragma unroll
    for (int o = 128; o > 0; o >>= 1) {
        if (t < o) s[t] += s[t + o];
        __syncthreads();
    }
    return s[0];
}

__device__ __forceinline__ int tri_invert(int n) {
    // largest i with i(i-1)/2 <= n
    int i = (int)((1.0f + sqrtf(8.0f * (float)n + 1.0f)) * 0.5f);
    while (i * (i - 1) / 2 > n) --i;
    while (i * (i - 1) / 2 + i <= n) ++i;
    return i;
}

// ---- prep A: J fp32 -> Jt fp8 transpose + reg_J; bulk streaming ----
__global__ __launch_bounds__(256) void k_prep(const float* __restrict__ J,
                                              unsigned* __restrict__ Jt,
                                              float* __restrict__ acc) {
    __shared__ float sB[PPB * QQ];   // 28224 B
    const int t = threadIdx.x;
    const int n0 = blockIdx.x * PPB;

    float v2acc = 0.f;
#pragma unroll 1
    for (int p = 0; p < PPB; ++p) {
        const int n = n0 + p;
        const int i = tri_invert(n);
        const int j = n - i * (i - 1) / 2;
        const float* blk = J + ((size_t)i * L_ + j) * QQ;
        float* dst = sB + p * QQ;
        for (int x = t; x < QQ; x += 256) {
            float v = blk[x];
            dst[x] = v;
            v2acc += v * v;
        }
    }
    __syncthreads();

    // pack: thread t handles pair p = t>>4, dwords d = (t&15) + 16u
    {
        const int p = t >> 4;
        const int n = n0 + p;
        const int i = tri_invert(n);
        const int j = n - i * (i - 1) / 2;
        const size_t ij = (size_t)i * L_ + j;
        const float* s = sB + p * QQ;
#pragma unroll
        for (int u = 0; u < 8; ++u) {
            const int d = (t & 15) + (u << 4);       // 0..127
            const int kr = d / 6;
            const int dw = d - 6 * kr;
            const int a0 = dw * 4;
            unsigned outw = 0;
            if (kr < Q_) {
                float x0 = (a0 + 0 < Q_) ? s[(a0 + 0) * Q_ + kr] : 0.f;
                float x1 = (a0 + 1 < Q_) ? s[(a0 + 1) * Q_ + kr] : 0.f;
                float x2 = (a0 + 2 < Q_) ? s[(a0 + 2) * Q_ + kr] : 0.f;
                float x3 = (a0 + 3 < Q_) ? s[(a0 + 3) * Q_ + kr] : 0.f;
                outw = (unsigned)__builtin_amdgcn_cvt_pk_fp8_f32(x0 * SCALE, x1 * SCALE, 0, false);
                outw = (unsigned)__builtin_amdgcn_cvt_pk_fp8_f32(x2 * SCALE, x3 * SCALE, (int)outw, true);
            }
            Jt[ij * 128 + d] = outw;
        }
    }

    float r = block_reduce_sum(v2acc);
    if (t == 0) atomicAdd(&acc[4 + (blockIdx.x & 255)], r);
}

// ---- prep B: pack seqs + wsum + h2 (33 small blocks) ----
__global__ __launch_bounds__(256) void k_prep2(const int* __restrict__ seqs,
                                               const float* __restrict__ w,
                                               const float* __restrict__ h,
                                               unsigned* __restrict__ seqsP,
                                               float* __restrict__ acc) {
    const int bid = blockIdx.x;
    const int t = threadIdx.x;
    if (bid < 32) {
        const int b = bid * 256 + t;
        const int4* row = reinterpret_cast<const int4*>(seqs + (size_t)b * L_);
#pragma unroll 4
        for (int jq = 0; jq < L_ / 4; ++jq) {
            int4 v = row[jq];
            unsigned p = (unsigned)(v.x & 255) | ((unsigned)(v.y & 255) << 8) |
                         ((unsigned)(v.z & 255) << 16) | ((unsigned)(v.w & 255) << 24);
            seqsP[jq * M_ + b] = p;
        }
    } else {
        float v = 0.f;
        for (int x = t; x < M_; x += 256) v += w[x];
        float r = block_reduce_sum(v);
        if (t == 0) acc[0] = r;
        float v2 = 0.f;
        for (int x = t; x < L_ * Q_; x += 256) { float y = h[x]; v2 += y * y; }
        float r2 = block_reduce_sum(v2);
        if (t == 0) acc[2] = r2;
    }
}

// Inner body: decode row k of staged block jj, accumulate 21 logits.
#define BODY(jj)                                                                   \
    {                                                                              \
        const unsigned kk = (idxw[(jj) >> 2] >> (((jj) & 3) * 8)) & 255u;          \
        const uint2* r = reinterpret_cast<const uint2*>(sJ) + ((jj) * 64 + kk * 3);\
        uint2 d0 = r[0], d1 = r[1], d2 = r[2];                                     \
        acc2[0]  += __builtin_amdgcn_cvt_pk_f32_fp8(d0.x, false);                  \
        acc2[1]  += __builtin_amdgcn_cvt_pk_f32_fp8(d0.x, true);                   \
        acc2[2]  += __builtin_amdgcn_cvt_pk_f32_fp8(d0.y, false);                  \
        acc2[3]  += __builtin_amdgcn_cvt_pk_f32_fp8(d0.y, true);                   \
        acc2[4]  += __builtin_amdgcn_cvt_pk_f32_fp8(d1.x, false);                  \
        acc2[5]  += __builtin_amdgcn_cvt_pk_f32_fp8(d1.x, true);                   \
        acc2[6]  += __builtin_amdgcn_cvt_pk_f32_fp8(d1.y, false);                  \
        acc2[7]  += __builtin_amdgcn_cvt_pk_f32_fp8(d1.y, true);                   \
        acc2[8]  += __builtin_amdgcn_cvt_pk_f32_fp8(d2.x, false);                  \
        acc2[9]  += __builtin_amdgcn_cvt_pk_f32_fp8(d2.x, true);                   \
        acc2[10] += __builtin_amdgcn_cvt_pk_f32_fp8(d2.y, false);                  \
    }

// ---- main: LDS-staged fp8 gather + log_softmax + weighted ll ----
__global__ __launch_bounds__(256, 8) void k_main(const unsigned* __restrict__ Jt,
                                                 const float* __restrict__ h,
                                                 const unsigned* __restrict__ seqsP,
                                                 const float* __restrict__ weights,
                                                 float* __restrict__ acc) {
    __shared__ unsigned sJ[JCH * 128];   // 16 KiB: JCH blocks x 128 dwords

    const int bid = blockIdx.x;
    const int i = (L_ - 1) - (bid >> 5);              // heavy blocks first
    const int b = ((bid & 31) << 8) + threadIdx.x;    // [0, 8192)

    // packed accumulators: acc2[m] covers logits a=2m, 2m+1 (scaled by SCALE)
    v2f acc2[11];
    const float* hp = h + i * Q_;
#pragma unroll
    for (int m = 0; m < 10; ++m) { acc2[m].x = hp[2*m] * SCALE; acc2[m].y = hp[2*m+1] * SCALE; }
    acc2[10].x = hp[20] * SCALE; acc2[10].y = 0.f;

    const unsigned* Jrow = Jt + (size_t)i * (256 * 128);  // dwords of row i

    const int nStages = i >> 5;   // full 32-j stages
    const int rem     = i & 31;

    for (int s = 0; s < nStages; ++s) {
        const int j0 = s << 5;
        {
            const uint4* src = reinterpret_cast<const uint4*>(Jrow + j0 * 128);
            uint4* dst = reinterpret_cast<uint4*>(sJ);
#pragma unroll
            for (int n = 0; n < (JCH * 32) / 256; ++n) {
                dst[n * 256 + threadIdx.x] = src[n * 256 + threadIdx.x];
            }
        }
        __syncthreads();

        unsigned idxw[JCH / 4];
#pragma unroll
        for (int q = 0; q < JCH / 4; ++q) {
            idxw[q] = seqsP[((j0 >> 2) + q) * M_ + b];
        }

        // clean 32-deep unroll — no per-jj conditionals
#pragma unroll
        for (int jj = 0; jj < JCH; ++jj) BODY(jj);

        __syncthreads();
    }

    if (rem) {
        const int j0 = nStages << 5;   // <= 224; staging j0..j0+31 always in-bounds
        {
            const uint4* src = reinterpret_cast<const uint4*>(Jrow + j0 * 128);
            uint4* dst = reinterpret_cast<uint4*>(sJ);
#pragma unroll
            for (int n = 0; n < (JCH * 32) / 256; ++n) {
                dst[n * 256 + threadIdx.x] = src[n * 256 + threadIdx.x];
            }
        }
        __syncthreads();

        unsigned idxw[JCH / 4];
#pragma unroll
        for (int q = 0; q < JCH / 4; ++q) {
            idxw[q] = seqsP[((j0 >> 2) + q) * M_ + b];
        }

#pragma unroll
        for (int jj = 0; jj < JCH; ++jj) {
            if (jj >= rem) break;
            BODY(jj);
        }
    }

    // unpack logits
    float l[21];
#pragma unroll
    for (int m = 0; m < 10; ++m) { l[2*m] = acc2[m].x * INVSCALE; l[2*m+1] = acc2[m].y * INVSCALE; }
    l[20] = acc2[10].x * INVSCALE;

    // label gather from packed seqs
    unsigned lw = seqsP[(i >> 2) * M_ + b];
    int lbl = (int)((lw >> ((i & 3) * 8)) & 255u);

    float m = l[0];
#pragma unroll
    for (int a = 1; a < 21; ++a) m = fmaxf(m, l[a]);
    float s = 0.f;
    float lv = l[0];
#pragma unroll
    for (int a = 0; a < 21; ++a) {
        s += __expf(l[a] - m);
        if (a > 0) lv = (a == lbl) ? l[a] : lv;
    }
    float ll = (lv - m) - __logf(s);
    float contrib = weights[b] * ll;

    float r = block_reduce_sum(contrib);
    if (threadIdx.x == 0) atomicAdd(&acc[260 + (bid & 127)], r);
}

// ---- finalize: reduce partial slots + compose outputs ----
__global__ void k_final(const float* __restrict__ acc, float* __restrict__ out) {
    int t = threadIdx.x;
    float j2p = acc[4 + t];                       // 256 J2 slots
    float j2 = block_reduce_sum(j2p);
    float llp = (t < 128) ? acc[260 + t] : 0.f;   // 128 ll slots
    float lls = block_reduce_sum(llp);
    if (t == 0) {
        float wsum = fmaxf(acc[0], 1e-12f);
        float nll = -lls / wsum;
        float reg = 0.5e-6f * acc[2] + 0.5e-4f * j2;
        out[0] = nll + reg;
        out[1] = nll;
        out[2] = reg;
    }
}

extern "C" void kernel_launch(void* const* d_in, const int* in_sizes, int n_in,
                              void* d_out, int out_size, void* d_ws, size_t ws_size,
                              hipStream_t stream) {
    const int*   seqs    = (const int*)d_in[0];
    const float* weights = (const float*)d_in[1];
    const float* h       = (const float*)d_in[2];
    const float* J       = (const float*)d_in[3];
    float* out = (float*)d_out;

    char* ws = (char*)d_ws;
    float*    acc   = (float*)ws;
    unsigned* seqsP = (unsigned*)(ws + 2048);
    unsigned* Jt    = (unsigned*)(ws + 2048 + (size_t)(L_ / 4) * M_ * sizeof(unsigned));

    hipMemsetAsync(d_ws, 0, 2048, stream);

    k_prep<<<PREPB, 256, 0, stream>>>(J, Jt, acc);
    k_prep2<<<33, 256, 0, stream>>>(seqs, weights, h, seqsP, acc);
    k_main<<<L_ * (M_ / 256), 256, 0, stream>>>(Jt, h, seqsP, weights, acc);
    k_final<<<1, 256, 0, stream>>>(acc, out);
}

// Round 8
// 416.756 us; speedup vs baseline: 1.0636x; 1.0295x over previous
//
#include <hip/hip_runtime.h>
#include <cstdint>
#include <cstddef>

// Problem constants
#define L_   256
#define Q_   21
#define M_   8192
#define QQ   441
#define JCH  16            // j-blocks staged per barrier in k_main
#define SCALE    32.0f     // J scaled by 32 before fp16 quantization
#define INVSCALE 0.03125f
#define NPAIR ((L_ * (L_ - 1)) / 2)   // 32640 valid (i,j) pairs
#define PPB   16           // pairs per prep block
#define PREPB (NPAIR / PPB)           // 2040 blocks, exact

// Jt block layout (per (i,j)): 21 rows (k = symbol), each row 48 B =
// 21 fp16(J*32) elems a=0..20 + 3 zero pad halves. Row stride 12 dwords.
// Block = 21*48 B padded to 1024 B (256 dwords). Jt = 65536 KiB = 64 MiB.
//
// ws layout (floats at base):
//   acc[0]=wsum  acc[2]=h2_sum
//   acc[4..259]   = 256 J2 partial slots
//   acc[260..387] = 128 ll partial slots
//   [2048 .. +2MiB)  seqsP: dword[jq*M + b] = symbols j=4jq..4jq+3 (bytes)
//   [2048+2MiB ..)   Jt (fp16 blocks)

typedef _Float16 h2 __attribute__((ext_vector_type(2)));

__device__ __forceinline__ float block_reduce_sum(float v) {
    __shared__ float s[256];
    int t = threadIdx.x;
    __syncthreads();           // guard against reuse hazard
    s[t] = v;
    __syncthreads();
#pragma unroll
    for (int o = 128; o > 0; o >>= 1) {
        if (t < o) s[t] += s[t + o];
        __syncthreads();
    }
    return s[0];
}

__device__ __forceinline__ int tri_invert(int n) {
    // largest i with i(i-1)/2 <= n
    int i = (int)((1.0f + sqrtf(8.0f * (float)n + 1.0f)) * 0.5f);
    while (i * (i - 1) / 2 > n) --i;
    while (i * (i - 1) / 2 + i <= n) ++i;
    return i;
}

// ---- prep A: J fp32 -> Jt fp16 transpose + reg_J; bulk streaming ----
__global__ __launch_bounds__(256) void k_prep(const float* __restrict__ J,
                                              unsigned* __restrict__ Jt,
                                              float* __restrict__ acc) {
    __shared__ float sB[PPB * QQ];   // 28224 B
    const int t = threadIdx.x;
    const int n0 = blockIdx.x * PPB;

    float v2acc = 0.f;
#pragma unroll 1
    for (int p = 0; p < PPB; ++p) {
        const int n = n0 + p;
        const int i = tri_invert(n);
        const int j = n - i * (i - 1) / 2;
        const float* blk = J + ((size_t)i * L_ + j) * QQ;
        float* dst = sB + p * QQ;
        for (int x = t; x < QQ; x += 256) {
            float v = blk[x];
            dst[x] = v;
            v2acc += v * v;
        }
    }
    __syncthreads();

    // pack: thread t handles pair p = t>>4, dwords d = (t&15) + 16u, u<16
    {
        const int p = t >> 4;
        const int n = n0 + p;
        const int i = tri_invert(n);
        const int j = n - i * (i - 1) / 2;
        const size_t ij = (size_t)i * L_ + j;
        const float* s = sB + p * QQ;
#pragma unroll
        for (int u = 0; u < 16; ++u) {
            const int d = (t & 15) + (u << 4);       // 0..255
            const int kr = d / 12;
            const int dw = d - 12 * kr;
            const int a0 = dw * 2;
            unsigned outw = 0;
            if (kr < Q_) {
                float x0 = (a0 + 0 < Q_) ? s[(a0 + 0) * Q_ + kr] : 0.f;
                float x1 = (a0 + 1 < Q_) ? s[(a0 + 1) * Q_ + kr] : 0.f;
                union { _Float16 hh[2]; unsigned u; } uu;
                uu.hh[0] = (_Float16)(x0 * SCALE);
                uu.hh[1] = (_Float16)(x1 * SCALE);
                outw = uu.u;
            }
            Jt[ij * 256 + d] = outw;
        }
    }

    float r = block_reduce_sum(v2acc);
    if (t == 0) atomicAdd(&acc[4 + (blockIdx.x & 255)], r);
}

// ---- prep B: pack seqs + wsum + h2 (33 small blocks) ----
__global__ __launch_bounds__(256) void k_prep2(const int* __restrict__ seqs,
                                               const float* __restrict__ w,
                                               const float* __restrict__ h,
                                               unsigned* __restrict__ seqsP,
                                               float* __restrict__ acc) {
    const int bid = blockIdx.x;
    const int t = threadIdx.x;
    if (bid < 32) {
        const int b = bid * 256 + t;
        const int4* row = reinterpret_cast<const int4*>(seqs + (size_t)b * L_);
#pragma unroll 4
        for (int jq = 0; jq < L_ / 4; ++jq) {
            int4 v = row[jq];
            unsigned p = (unsigned)(v.x & 255) | ((unsigned)(v.y & 255) << 8) |
                         ((unsigned)(v.z & 255) << 16) | ((unsigned)(v.w & 255) << 24);
            seqsP[jq * M_ + b] = p;
        }
    } else {
        float v = 0.f;
        for (int x = t; x < M_; x += 256) v += w[x];
        float r = block_reduce_sum(v);
        if (t == 0) acc[0] = r;
        float v2 = 0.f;
        for (int x = t; x < L_ * Q_; x += 256) { float y = h[x]; v2 += y * y; }
        float r2 = block_reduce_sum(v2);
        if (t == 0) acc[2] = r2;
    }
}

// Inner body: row k of staged block jj, 12 packed fp16 adds (24 halves incl pad).
#define BODY(jj)                                                                    \
    {                                                                               \
        const unsigned kk = (idxw[(jj) >> 2] >> (((jj) & 3) * 8)) & 255u;           \
        const uint4* rp = reinterpret_cast<const uint4*>(sJ) + ((jj) * 64 + kk * 3);\
        union { uint4 u; h2 h[4]; } ra, rb, rc;                                     \
        ra.u = rp[0]; rb.u = rp[1]; rc.u = rp[2];                                   \
        acch[0]  += ra.h[0]; acch[1]  += ra.h[1];                                   \
        acch[2]  += ra.h[2]; acch[3]  += ra.h[3];                                   \
        acch[4]  += rb.h[0]; acch[5]  += rb.h[1];                                   \
        acch[6]  += rb.h[2]; acch[7]  += rb.h[3];                                   \
        acch[8]  += rc.h[0]; acch[9]  += rc.h[1];                                   \
        acch[10] += rc.h[2]; acch[11] += rc.h[3];                                   \
    }

// ---- main: LDS-staged fp16 gather, packed-fp16 accumulate ----
__global__ __launch_bounds__(256, 8) void k_main(const unsigned* __restrict__ Jt,
                                                 const float* __restrict__ h,
                                                 const unsigned* __restrict__ seqsP,
                                                 const float* __restrict__ weights,
                                                 float* __restrict__ acc) {
    __shared__ unsigned sJ[JCH * 256];   // 16 KiB: JCH blocks x 256 dwords

    const int bid = blockIdx.x;
    const int i = (L_ - 1) - (bid >> 5);              // heavy blocks first
    const int b = ((bid & 31) << 8) + threadIdx.x;    // [0, 8192)

    // packed fp16 accumulators (scaled by SCALE); elems 21..23 stay ~0 (pads)
    h2 acch[12];
    const float* hp = h + i * Q_;
#pragma unroll
    for (int m = 0; m < 10; ++m) {
        acch[m].x = (_Float16)(hp[2 * m] * SCALE);
        acch[m].y = (_Float16)(hp[2 * m + 1] * SCALE);
    }
    acch[10].x = (_Float16)(hp[20] * SCALE); acch[10].y = (_Float16)0.f;
    acch[11].x = (_Float16)0.f;              acch[11].y = (_Float16)0.f;

    const unsigned* Jrow = Jt + (size_t)i * (256 * 256);  // dwords of row i

    const int nStages = i >> 4;   // full 16-j stages
    const int rem     = i & 15;

    for (int s = 0; s < nStages; ++s) {
        const int j0 = s << 4;
        {
            const uint4* src = reinterpret_cast<const uint4*>(Jrow + j0 * 256);
            uint4* dst = reinterpret_cast<uint4*>(sJ);
#pragma unroll
            for (int n = 0; n < 4; ++n) {
                dst[n * 256 + threadIdx.x] = src[n * 256 + threadIdx.x];
            }
        }
        __syncthreads();

        unsigned idxw[JCH / 4];
#pragma unroll
        for (int q = 0; q < JCH / 4; ++q) {
            idxw[q] = seqsP[((j0 >> 2) + q) * M_ + b];
        }

#pragma unroll
        for (int jj = 0; jj < JCH; ++jj) BODY(jj);

        __syncthreads();
    }

    if (rem) {
        const int j0 = nStages << 4;   // <= 240; staging j0..j0+15 in-bounds
        {
            const uint4* src = reinterpret_cast<const uint4*>(Jrow + j0 * 256);
            uint4* dst = reinterpret_cast<uint4*>(sJ);
#pragma unroll
            for (int n = 0; n < 4; ++n) {
                dst[n * 256 + threadIdx.x] = src[n * 256 + threadIdx.x];
            }
        }
        __syncthreads();

        unsigned idxw[JCH / 4];
#pragma unroll
        for (int q = 0; q < JCH / 4; ++q) {
            idxw[q] = seqsP[((j0 >> 2) + q) * M_ + b];
        }

#pragma unroll
        for (int jj = 0; jj < JCH; ++jj) {
            if (jj >= rem) break;
            BODY(jj);
        }
    }

    // unpack logits to fp32
    float l[21];
#pragma unroll
    for (int m = 0; m < 10; ++m) {
        l[2 * m]     = (float)acch[m].x * INVSCALE;
        l[2 * m + 1] = (float)acch[m].y * INVSCALE;
    }
    l[20] = (float)acch[10].x * INVSCALE;

    // label gather from packed seqs
    unsigned lw = seqsP[(i >> 2) * M_ + b];
    int lbl = (int)((lw >> ((i & 3) * 8)) & 255u);

    float m = l[0];
#pragma unroll
    for (int a = 1; a < 21; ++a) m = fmaxf(m, l[a]);
    float s = 0.f;
    float lv = l[0];
#pragma unroll
    for (int a = 0; a < 21; ++a) {
        s += __expf(l[a] - m);
        if (a > 0) lv = (a == lbl) ? l[a] : lv;
    }
    float ll = (lv - m) - __logf(s);
    float contrib = weights[b] * ll;

    float r = block_reduce_sum(contrib);
    if (threadIdx.x == 0) atomicAdd(&acc[260 + (bid & 127)], r);
}

// ---- finalize: reduce partial slots + compose outputs ----
__global__ void k_final(const float* __restrict__ acc, float* __restrict__ out) {
    int t = threadIdx.x;
    float j2p = acc[4 + t];                       // 256 J2 slots
    float j2 = block_reduce_sum(j2p);
    float llp = (t < 128) ? acc[260 + t] : 0.f;   // 128 ll slots
    float lls = block_reduce_sum(llp);
    if (t == 0) {
        float wsum = fmaxf(acc[0], 1e-12f);
        float nll = -lls / wsum;
        float reg = 0.5e-6f * acc[2] + 0.5e-4f * j2;
        out[0] = nll + reg;
        out[1] = nll;
        out[2] = reg;
    }
}

extern "C" void kernel_launch(void* const* d_in, const int* in_sizes, int n_in,
                              void* d_out, int out_size, void* d_ws, size_t ws_size,
                              hipStream_t stream) {
    const int*   seqs    = (const int*)d_in[0];
    const float* weights = (const float*)d_in[1];
    const float* h       = (const float*)d_in[2];
    const float* J       = (const float*)d_in[3];
    float* out = (float*)d_out;

    char* ws = (char*)d_ws;
    float*    acc   = (float*)ws;
    unsigned* seqsP = (unsigned*)(ws + 2048);
    unsigned* Jt    = (unsigned*)(ws + 2048 + (size_t)(L_ / 4) * M_ * sizeof(unsigned));

    hipMemsetAsync(d_ws, 0, 2048, stream);

    k_prep<<<PREPB, 256, 0, stream>>>(J, Jt, acc);
    k_prep2<<<33, 256, 0, stream>>>(seqs, weights, h, seqsP, acc);
    k_main<<<L_ * (M_ / 256), 256, 0, stream>>>(Jt, h, seqsP, weights, acc);
    k_final<<<1, 256, 0, stream>>>(acc, out);
}